// Round 2
// baseline (238.877 us; speedup 1.0000x reference)
//
#include <hip/hip_runtime.h>
#include <stdint.h>

// Problem: x[B=32][N=8192][D=64] fp32 -> out[B][D][D][D] fp32 (centered 3rd moment)
#define B_SZ 32
#define N_SZ 8192
#define D_SZ 64

typedef _Float16 half8 __attribute__((ext_vector_type(8)));
typedef float f32x4 __attribute__((ext_vector_type(4)));

#define AS1 __attribute__((address_space(1)))
#define AS3 __attribute__((address_space(3)))

#define MFMA16(Aop, Bop, Cop) __builtin_amdgcn_mfma_f32_16x16x32_f16(Aop, Bop, Cop, 0, 0, 0)

// Granule layout v1 (R3/R5-proven 0-conflict): per 64-n granule, chunk (d, cc)
// [8 halves, n = cc*8..+8] stored at d*64 + (cc ^ (d&7))*8 halves.
// v2 (R1): gemm as 4 N-quarter waves x ej=4; each granule LDS-read by exactly
// ONE wave (16 b128 -> 80 MFMA); barrier-free main loop with per-wave
// vmcnt(8)/lgkmcnt(0) double-buffer discipline.
// v2.1 (this round): __launch_bounds__(256, 2) -> (256, 1).
//   R1 post-mortem: acc[4][10] (160 regs) + ~112 arch regs = ~272 > the
//   256-reg unified budget implied by min-2-waves/EU => compiler spilled the
//   accumulators to scratch (WRITE_SIZE 33->297 MB, MfmaUtil 50->0.3%).
//   min-1-wave/EU raises the budget to 512; acc stays in the unified file.
//   Cost: 1 wave/SIMD -- MFMA pipelining must come from the 10 independent
//   acc chains (ILP), not TLP. Expected per-iter bubble ~8-12% over the
//   41.4 us matrix floor.

// ---------------------------------------------------------------------------
// Kernel 1: per-batch column sums. grid = 32 b * 32 slabs (256 n-rows each).
// ---------------------------------------------------------------------------
__global__ __launch_bounds__(256) void tp_mean_kernel(const float* __restrict__ x,
                                                      float* __restrict__ sums) {
    const int b    = blockIdx.x >> 5;
    const int slab = blockIdx.x & 31;
    const int d4   = threadIdx.x & 15;
    const int nr   = threadIdx.x >> 4;
    const float* base = x + (size_t)b * (N_SZ * D_SZ) + (size_t)(slab * 256 + nr) * D_SZ + d4 * 4;
    f32x4 s = {0.f, 0.f, 0.f, 0.f};
#pragma unroll
    for (int i = 0; i < 16; i++)
        s += *(const f32x4*)(base + i * 16 * D_SZ);
    __shared__ f32x4 red[16][16];
    red[nr][d4] = s;
    __syncthreads();
    if (threadIdx.x < 16) {
        f32x4 tot = red[0][threadIdx.x];
#pragma unroll
        for (int j = 1; j < 16; j++) tot += red[j][threadIdx.x];
        atomicAdd(&sums[b * 64 + threadIdx.x * 4 + 0], tot[0]);
        atomicAdd(&sums[b * 64 + threadIdx.x * 4 + 1], tot[1]);
        atomicAdd(&sums[b * 64 + threadIdx.x * 4 + 2], tot[2]);
        atomicAdd(&sums[b * 64 + threadIdx.x * 4 + 3], tot[3]);
    }
}

// ---------------------------------------------------------------------------
// Kernel 2: center, cast fp16, register transpose into layout v1 (R3 verbatim).
// ---------------------------------------------------------------------------
__global__ __launch_bounds__(256) void tp_transpose_kernel(const float* __restrict__ x,
                                                           const float* __restrict__ sums,
                                                           _Float16* __restrict__ xcS) {
    const int b    = blockIdx.x >> 6;
    const int tp   = blockIdx.x & 63;
    const int t    = threadIdx.x;
    const int tile = tp * 2 + (t >> 7);
    const int r8   = (t >> 4) & 7;
    const int dq   = t & 15;

    f32x4 mean4 = *(const f32x4*)(sums + b * 64 + dq * 4) * (1.0f / (float)N_SZ);
    const float* src = x + (size_t)b * (N_SZ * D_SZ) + (size_t)(tile * 64 + r8 * 8) * D_SZ + dq * 4;
    f32x4 v[8];
#pragma unroll
    for (int i = 0; i < 8; i++)
        v[i] = *(const f32x4*)(src + i * D_SZ);

    _Float16* dstb = xcS + (size_t)b * (N_SZ * D_SZ) + (size_t)tile * 4096;
#pragma unroll
    for (int c = 0; c < 4; c++) {
        const int d   = dq * 4 + c;
        const int ccp = r8 ^ (d & 7);
        half8 o;
#pragma unroll
        for (int i = 0; i < 8; i++)
            o[i] = (_Float16)(v[i][c] - mean4[c]);
        *(half8*)(dstb + d * 64 + ccp * 8) = o;
    }
}

// ---------------------------------------------------------------------------
// Kernel 3 v2.1: 4 waves = 4 N-quarters, each wave computes ej=4 e-values.
// grid = (32 b, 16 eg), block 256 thr, LDS = 2 bufs x 4 h x 8KB = 64KB.
// Per wave per T (one 64-n granule): 16 ds_read_b128 -> 80 MFMA;
// acc[4][10] f32x4 = 160 regs, kept in the unified file via min-1-wave/EU.
// Main loop barrier-free (wave-private buffers), per-wave vmcnt(8) pipeline.
// 4-way cross-h reduction epilogue in two rounds; stores split between
// waves h=0 (e0,e0+1) and h=1 (e0+2,e0+3).
// ---------------------------------------------------------------------------
__global__ __launch_bounds__(256, 1) void tp_gemm_kernel(const _Float16* __restrict__ xcS,
                                                         float* __restrict__ out) {
    const int b    = blockIdx.x;          // 0..31
    const int eg   = blockIdx.y;          // 0..15
    const int tid  = threadIdx.x;
    const int lane = tid & 63;
    const int h    = tid >> 6;            // 0..3 N-quarter
    const int q    = lane >> 4;           // 0..3
    const int m    = lane & 15;
    const int e0   = eg * 4;

    __shared__ __align__(16) char ldsraw[65536];   // 2 bufs x 4 h x 8KB
    float* redL = (float*)ldsraw;                  // aliased for reduction (60KB)

    // staging source: wave h owns quarter h, one full 8KB granule per T
    const _Float16* gbase = xcS + (size_t)b * (N_SZ * D_SZ)
                          + (size_t)h * (N_SZ / 4) * D_SZ
                          + (size_t)(lane * 8);

    // fragment byte offsets (layout v1) for ks=0; ks=1 is offset ^ 64
    // (c = ks*4+q = q^4 for ks=1, and (x^4)*16 = x*16 ^ 64).
    int aOff[4], sOff[4];
#pragma unroll
    for (int i = 0; i < 4; i++) {
        const int r = i * 16 + m;
        aOff[i] = r * 128 + ((q ^ (r & 7)) * 16);
    }
#pragma unroll
    for (int j = 0; j < 4; j++) {
        const int e = e0 + j;
        sOff[j] = e * 128 + ((q ^ (e & 7)) * 16);
    }

    f32x4 acc[4][10];
#pragma unroll
    for (int ej = 0; ej < 4; ej++)
#pragma unroll
        for (int k = 0; k < 10; k++)
            acc[ej][k] = (f32x4){0.f, 0.f, 0.f, 0.f};

    // stage granule T of my quarter into buffer bi (wave-private 8KB region)
    auto stage = [&](int T, int bi) {
        _Float16* lb = (_Float16*)(ldsraw + bi * 32768 + h * 8192);
        const _Float16* gb = gbase + (size_t)T * 4096;
#pragma unroll
        for (int k = 0; k < 8; k++)
            __builtin_amdgcn_global_load_lds(
                (const AS1 void*)(gb + k * 512),
                (AS3 void*)(lb + k * 512), 16, 0, 0);
    };

    stage(0, 0);

    for (int T = 0; T < 32; T++) {
        if (T < 31) {
            // all prior ds_reads must have pulled their data out of the
            // buffer stage(T+1) is about to overwrite
            asm volatile("s_waitcnt lgkmcnt(0)" ::: "memory");
            stage(T + 1, (T + 1) & 1);
            // oldest 8 loads (granule T) done; next 8 stay in flight
            asm volatile("s_waitcnt vmcnt(8)" ::: "memory");
        } else {
            asm volatile("s_waitcnt vmcnt(0)" ::: "memory");
        }
        const char* tb = ldsraw + (T & 1) * 32768 + h * 8192;
#pragma unroll
        for (int ks = 0; ks < 2; ks++) {
            const int kx = ks << 6;
            half8 A0 = *(const half8*)(tb + (aOff[0] ^ kx));
            half8 A1 = *(const half8*)(tb + (aOff[1] ^ kx));
            half8 A2 = *(const half8*)(tb + (aOff[2] ^ kx));
            half8 A3 = *(const half8*)(tb + (aOff[3] ^ kx));
#pragma unroll
            for (int ej = 0; ej < 4; ej++) {
                half8 S  = *(const half8*)(tb + (sOff[ej] ^ kx));
                half8 P0 = A0 * S;    // fold xc[n,e] into A (v_pk_mul_f16)
                half8 P1 = A1 * S;
                half8 P2 = A2 * S;
                half8 P3 = A3 * S;
                acc[ej][0] = MFMA16(P0, A0, acc[ej][0]);
                acc[ej][1] = MFMA16(P0, A1, acc[ej][1]);
                acc[ej][2] = MFMA16(P0, A2, acc[ej][2]);
                acc[ej][3] = MFMA16(P0, A3, acc[ej][3]);
                acc[ej][4] = MFMA16(P1, A1, acc[ej][4]);
                acc[ej][5] = MFMA16(P1, A2, acc[ej][5]);
                acc[ej][6] = MFMA16(P1, A3, acc[ej][6]);
                acc[ej][7] = MFMA16(P2, A2, acc[ej][7]);
                acc[ej][8] = MFMA16(P2, A3, acc[ej][8]);
                acc[ej][9] = MFMA16(P3, A3, acc[ej][9]);
            }
        }
    }

    // ---- 4-way cross-h reduction, two rounds of 3 x 20KB dumps ----
    __syncthreads();                      // end of main loop, LDS alias reuse
    const int rb = lane * 4;
    // round 0: h=1,2,3 dump acc[0..1]; h=0 gathers (owns e0, e0+1)
    if (h != 0) {
        float* dst = redL + (size_t)(h - 1) * 5120 + rb;
#pragma unroll
        for (int ej = 0; ej < 2; ej++)
#pragma unroll
            for (int k = 0; k < 10; k++)
                *(f32x4*)(dst + (ej * 10 + k) * 256) = acc[ej][k];
    }
    __syncthreads();
    if (h == 0) {
#pragma unroll
        for (int ej = 0; ej < 2; ej++)
#pragma unroll
            for (int k = 0; k < 10; k++) {
                const float* s0 = redL + (ej * 10 + k) * 256 + rb;
                acc[ej][k] += *(const f32x4*)(s0);
                acc[ej][k] += *(const f32x4*)(s0 + 5120);
                acc[ej][k] += *(const f32x4*)(s0 + 10240);
            }
    }
    __syncthreads();
    // round 1: h=0,2,3 dump acc[2..3]; h=1 gathers (owns e0+2, e0+3)
    if (h != 1) {
        const int region = (h == 0) ? 0 : (h - 1);
        float* dst = redL + (size_t)region * 5120 + rb;
#pragma unroll
        for (int ej = 0; ej < 2; ej++)
#pragma unroll
            for (int k = 0; k < 10; k++)
                *(f32x4*)(dst + (ej * 10 + k) * 256) = acc[2 + ej][k];
    }
    __syncthreads();
    if (h == 1) {
#pragma unroll
        for (int ej = 0; ej < 2; ej++)
#pragma unroll
            for (int k = 0; k < 10; k++) {
                const float* s0 = redL + (ej * 10 + k) * 256 + rb;
                acc[2 + ej][k] += *(const f32x4*)(s0);
                acc[2 + ej][k] += *(const f32x4*)(s0 + 5120);
                acc[2 + ej][k] += *(const f32x4*)(s0 + 10240);
            }
    }

    // ---- stores: wave h=0 writes e0..e0+1, wave h=1 writes e0+2..e0+3 ----
    if (h < 2) {
        const float invn = 1.0f / (float)N_SZ;
        float* outb = out + (size_t)b * (D_SZ * D_SZ * D_SZ);
#pragma unroll
        for (int ejL = 0; ejL < 2; ejL++) {
            const int ej = h * 2 + ejL;
            const int e  = e0 + ej;
            int idx = 0;
            // C/D layout (verified): col = lane&15 = f-within-block, row = q*4+reg
#pragma unroll
            for (int i = 0; i < 4; i++) {
#pragma unroll
                for (int j = i; j < 4; j++, idx++) {
                    f32x4 vsc = acc[ej][idx] * invn;
#pragma unroll
                    for (int r = 0; r < 4; r++)
                        outb[(size_t)(16 * i + q * 4 + r) * 4096 + e * 64 + 16 * j + m] = vsc[r];
                    if (i != j) {
                        *(f32x4*)&outb[(size_t)(16 * j + m) * 4096 + e * 64 + 16 * i + q * 4] = vsc;
                    }
                }
            }
        }
    }
}

// ---------------------------------------------------------------------------
extern "C" void kernel_launch(void* const* d_in, const int* in_sizes, int n_in,
                              void* d_out, int out_size, void* d_ws, size_t ws_size,
                              hipStream_t stream) {
    const float* x = (const float*)d_in[0];
    float* out = (float*)d_out;

    float* sums = (float*)d_ws;                           // 8 KB
    _Float16* xcS = (_Float16*)((char*)d_ws + 8192);      // 33.5 MB fp16

    hipMemsetAsync(sums, 0, B_SZ * D_SZ * sizeof(float), stream);
    tp_mean_kernel<<<dim3(B_SZ * 32), 256, 0, stream>>>(x, sums);
    tp_transpose_kernel<<<dim3(B_SZ * 64), 256, 0, stream>>>(x, sums, xcS);
    tp_gemm_kernel<<<dim3(32, 16), 256, 0, stream>>>(xcS, out);
}

// Round 4
// 214.055 us; speedup vs baseline: 1.1160x; 1.1160x over previous
//
#include <hip/hip_runtime.h>
#include <stdint.h>

// Problem: x[B=32][N=8192][D=64] fp32 -> out[B][D][D][D] fp32 (centered 3rd moment)
#define B_SZ 32
#define N_SZ 8192
#define D_SZ 64

typedef _Float16 half8 __attribute__((ext_vector_type(8)));
typedef float f32x4 __attribute__((ext_vector_type(4)));

#define AS1 __attribute__((address_space(1)))
#define AS3 __attribute__((address_space(3)))

#define MFMA16(Aop, Bop, Cop) __builtin_amdgcn_mfma_f32_16x16x32_f16(Aop, Bop, Cop, 0, 0, 0)

// Granule layout v1 (proven 0-conflict): per 64-n granule, chunk (d, cc)
// [8 halves, n = cc*8..+8] stored at d*64 + (cc ^ (d&7))*8 halves.
//
// v3 (this round): revert to intrinsic MFMA (R3 post-mortem: inline-asm MFMA
//   bypasses the hazard recognizer's mandatory wait-states -> silent
//   corruption). Register constraint is now treated as hard: allocator
//   handles acc=80 in AGPRs (R0: 88 VGPR + correct) but spills acc=160
//   regardless of launch bounds (R1/R2). So: ej=2 per wave, eg doubled to 32.
//   KEPT from v2 (independent of ej): single-reader granules (wave h owns
//   N-quarter h; each granule LDS-read by exactly one wave: 12 b128 -> 40
//   MFMA) and the barrier-free main loop (wave-private double buffers,
//   lgkmcnt(0) before overwrite, vmcnt(8) pipeline).
//   Pipe model/CU: matrix 99k cyc; LDS 74k read + 32k stage-write = 106k.
//   LDS slightly critical; next lever if confirmed: S-reads global->reg.

// ---------------------------------------------------------------------------
// Kernel 1: per-batch column sums. grid = 32 b * 32 slabs (256 n-rows each).
// ---------------------------------------------------------------------------
__global__ __launch_bounds__(256) void tp_mean_kernel(const float* __restrict__ x,
                                                      float* __restrict__ sums) {
    const int b    = blockIdx.x >> 5;
    const int slab = blockIdx.x & 31;
    const int d4   = threadIdx.x & 15;
    const int nr   = threadIdx.x >> 4;
    const float* base = x + (size_t)b * (N_SZ * D_SZ) + (size_t)(slab * 256 + nr) * D_SZ + d4 * 4;
    f32x4 s = {0.f, 0.f, 0.f, 0.f};
#pragma unroll
    for (int i = 0; i < 16; i++)
        s += *(const f32x4*)(base + i * 16 * D_SZ);
    __shared__ f32x4 red[16][16];
    red[nr][d4] = s;
    __syncthreads();
    if (threadIdx.x < 16) {
        f32x4 tot = red[0][threadIdx.x];
#pragma unroll
        for (int j = 1; j < 16; j++) tot += red[j][threadIdx.x];
        atomicAdd(&sums[b * 64 + threadIdx.x * 4 + 0], tot[0]);
        atomicAdd(&sums[b * 64 + threadIdx.x * 4 + 1], tot[1]);
        atomicAdd(&sums[b * 64 + threadIdx.x * 4 + 2], tot[2]);
        atomicAdd(&sums[b * 64 + threadIdx.x * 4 + 3], tot[3]);
    }
}

// ---------------------------------------------------------------------------
// Kernel 2: center, cast fp16, register transpose into layout v1 (verbatim).
// ---------------------------------------------------------------------------
__global__ __launch_bounds__(256) void tp_transpose_kernel(const float* __restrict__ x,
                                                           const float* __restrict__ sums,
                                                           _Float16* __restrict__ xcS) {
    const int b    = blockIdx.x >> 6;
    const int tp   = blockIdx.x & 63;
    const int t    = threadIdx.x;
    const int tile = tp * 2 + (t >> 7);
    const int r8   = (t >> 4) & 7;
    const int dq   = t & 15;

    f32x4 mean4 = *(const f32x4*)(sums + b * 64 + dq * 4) * (1.0f / (float)N_SZ);
    const float* src = x + (size_t)b * (N_SZ * D_SZ) + (size_t)(tile * 64 + r8 * 8) * D_SZ + dq * 4;
    f32x4 v[8];
#pragma unroll
    for (int i = 0; i < 8; i++)
        v[i] = *(const f32x4*)(src + i * D_SZ);

    _Float16* dstb = xcS + (size_t)b * (N_SZ * D_SZ) + (size_t)tile * 4096;
#pragma unroll
    for (int c = 0; c < 4; c++) {
        const int d   = dq * 4 + c;
        const int ccp = r8 ^ (d & 7);
        half8 o;
#pragma unroll
        for (int i = 0; i < 8; i++)
            o[i] = (_Float16)(v[i][c] - mean4[c]);
        *(half8*)(dstb + d * 64 + ccp * 8) = o;
    }
}

// ---------------------------------------------------------------------------
// Kernel 3 v3: grid (32 b, 32 eg), block 256 = 4 waves = 4 N-quarters,
// each wave computes ej=2 e-values (e0 = eg*2). LDS = 2 bufs x 4 h x 8KB.
// Per wave per T (one 64-n granule): 12 ds_read_b128 -> 40 MFMA;
// acc[2][10] = 80 regs -> AGPRs by allocator heuristic (R0-proven).
// Main loop barrier-free (wave-private buffers), per-wave vmcnt(8) pipeline.
// 4-way cross-h reduction in two rounds; wave h=0 stores e0, h=1 stores e0+1.
// ---------------------------------------------------------------------------
__global__ __launch_bounds__(256, 2) void tp_gemm_kernel(const _Float16* __restrict__ xcS,
                                                         float* __restrict__ out) {
    const int b    = blockIdx.x;          // 0..31
    const int eg   = blockIdx.y;          // 0..31
    const int tid  = threadIdx.x;
    const int lane = tid & 63;
    const int h    = tid >> 6;            // 0..3 N-quarter
    const int q    = lane >> 4;           // 0..3
    const int m    = lane & 15;
    const int e0   = eg * 2;

    __shared__ __align__(16) char ldsraw[65536];   // 2 bufs x 4 h x 8KB
    float* redL = (float*)ldsraw;                  // aliased for reduction (30KB)

    // staging source: wave h owns quarter h, one full 8KB granule per T
    const _Float16* gbase = xcS + (size_t)b * (N_SZ * D_SZ)
                          + (size_t)h * (N_SZ / 4) * D_SZ
                          + (size_t)(lane * 8);

    // fragment byte offsets (layout v1) for ks=0; ks=1 is offset ^ 64
    // (c = ks*4+q = q^4 for ks=1, and (x^4)*16 = x*16 ^ 64).
    int aOff[4], sOff[2];
#pragma unroll
    for (int i = 0; i < 4; i++) {
        const int r = i * 16 + m;
        aOff[i] = r * 128 + ((q ^ (r & 7)) * 16);
    }
#pragma unroll
    for (int j = 0; j < 2; j++) {
        const int e = e0 + j;
        sOff[j] = e * 128 + ((q ^ (e & 7)) * 16);
    }

    f32x4 acc[2][10];
#pragma unroll
    for (int ej = 0; ej < 2; ej++)
#pragma unroll
        for (int k = 0; k < 10; k++)
            acc[ej][k] = (f32x4){0.f, 0.f, 0.f, 0.f};

    // stage granule T of my quarter into buffer bi (wave-private 8KB region)
    auto stage = [&](int T, int bi) {
        _Float16* lb = (_Float16*)(ldsraw + bi * 32768 + h * 8192);
        const _Float16* gb = gbase + (size_t)T * 4096;
#pragma unroll
        for (int k = 0; k < 8; k++)
            __builtin_amdgcn_global_load_lds(
                (const AS1 void*)(gb + k * 512),
                (AS3 void*)(lb + k * 512), 16, 0, 0);
    };

    stage(0, 0);

    for (int T = 0; T < 32; T++) {
        if (T < 31) {
            // all prior ds_reads must have pulled their data out of the
            // buffer stage(T+1) is about to overwrite
            asm volatile("s_waitcnt lgkmcnt(0)" ::: "memory");
            stage(T + 1, (T + 1) & 1);
            // oldest 8 loads (granule T) done; next 8 stay in flight
            asm volatile("s_waitcnt vmcnt(8)" ::: "memory");
        } else {
            asm volatile("s_waitcnt vmcnt(0)" ::: "memory");
        }
        const char* tb = ldsraw + (T & 1) * 32768 + h * 8192;
#pragma unroll
        for (int ks = 0; ks < 2; ks++) {
            const int kx = ks << 6;
            half8 A0 = *(const half8*)(tb + (aOff[0] ^ kx));
            half8 A1 = *(const half8*)(tb + (aOff[1] ^ kx));
            half8 A2 = *(const half8*)(tb + (aOff[2] ^ kx));
            half8 A3 = *(const half8*)(tb + (aOff[3] ^ kx));
#pragma unroll
            for (int ej = 0; ej < 2; ej++) {
                half8 S  = *(const half8*)(tb + (sOff[ej] ^ kx));
                half8 P0 = A0 * S;    // fold xc[n,e] into A (v_pk_mul_f16)
                half8 P1 = A1 * S;
                half8 P2 = A2 * S;
                half8 P3 = A3 * S;
                acc[ej][0] = MFMA16(P0, A0, acc[ej][0]);
                acc[ej][1] = MFMA16(P0, A1, acc[ej][1]);
                acc[ej][2] = MFMA16(P0, A2, acc[ej][2]);
                acc[ej][3] = MFMA16(P0, A3, acc[ej][3]);
                acc[ej][4] = MFMA16(P1, A1, acc[ej][4]);
                acc[ej][5] = MFMA16(P1, A2, acc[ej][5]);
                acc[ej][6] = MFMA16(P1, A3, acc[ej][6]);
                acc[ej][7] = MFMA16(P2, A2, acc[ej][7]);
                acc[ej][8] = MFMA16(P2, A3, acc[ej][8]);
                acc[ej][9] = MFMA16(P3, A3, acc[ej][9]);
            }
        }
    }

    // ---- 4-way cross-h reduction, two rounds (30KB dumps each) ----
    __syncthreads();                      // end of main loop, LDS alias reuse
    const int rb = lane * 4;
    // round 0: h=1,2,3 dump acc[0]; h=0 gathers (owns e0)
    if (h != 0) {
        float* dst = redL + (h - 1) * 2560 + rb;
#pragma unroll
        for (int k = 0; k < 10; k++)
            *(f32x4*)(dst + k * 256) = acc[0][k];
    }
    __syncthreads();
    if (h == 0) {
#pragma unroll
        for (int k = 0; k < 10; k++) {
            const float* s0 = redL + k * 256 + rb;
            acc[0][k] += *(const f32x4*)(s0);
            acc[0][k] += *(const f32x4*)(s0 + 2560);
            acc[0][k] += *(const f32x4*)(s0 + 5120);
        }
    }
    __syncthreads();
    // round 1: h=0,2,3 dump acc[1]; h=1 gathers (owns e0+1)
    if (h != 1) {
        const int region = (h == 0) ? 0 : (h - 1);
        float* dst = redL + region * 2560 + rb;
#pragma unroll
        for (int k = 0; k < 10; k++)
            *(f32x4*)(dst + k * 256) = acc[1][k];
    }
    __syncthreads();
    if (h == 1) {
#pragma unroll
        for (int k = 0; k < 10; k++) {
            const float* s0 = redL + k * 256 + rb;
            acc[1][k] += *(const f32x4*)(s0);
            acc[1][k] += *(const f32x4*)(s0 + 2560);
            acc[1][k] += *(const f32x4*)(s0 + 5120);
        }
    }

    // ---- stores: wave h stores e = e0 + h from acc[h] (h = 0, 1) ----
    if (h < 2) {
        const float invn = 1.0f / (float)N_SZ;
        float* outb = out + (size_t)b * (D_SZ * D_SZ * D_SZ);
        const int e = e0 + h;
        int idx = 0;
        // C/D layout (verified): col = lane&15 = f-within-block, row = q*4+reg
#pragma unroll
        for (int i = 0; i < 4; i++) {
#pragma unroll
            for (int j = i; j < 4; j++, idx++) {
                f32x4 vsc = acc[h][idx] * invn;
#pragma unroll
                for (int r = 0; r < 4; r++)
                    outb[(size_t)(16 * i + q * 4 + r) * 4096 + e * 64 + 16 * j + m] = vsc[r];
                if (i != j) {
                    *(f32x4*)&outb[(size_t)(16 * j + m) * 4096 + e * 64 + 16 * i + q * 4] = vsc;
                }
            }
        }
    }
}

// ---------------------------------------------------------------------------
extern "C" void kernel_launch(void* const* d_in, const int* in_sizes, int n_in,
                              void* d_out, int out_size, void* d_ws, size_t ws_size,
                              hipStream_t stream) {
    const float* x = (const float*)d_in[0];
    float* out = (float*)d_out;

    float* sums = (float*)d_ws;                           // 8 KB
    _Float16* xcS = (_Float16*)((char*)d_ws + 8192);      // 33.5 MB fp16

    hipMemsetAsync(sums, 0, B_SZ * D_SZ * sizeof(float), stream);
    tp_mean_kernel<<<dim3(B_SZ * 32), 256, 0, stream>>>(x, sums);
    tp_transpose_kernel<<<dim3(B_SZ * 64), 256, 0, stream>>>(x, sums, xcS);
    tp_gemm_kernel<<<dim3(32, 32), 256, 0, stream>>>(xcS, out);
}

// Round 5
// 195.467 us; speedup vs baseline: 1.2221x; 1.0951x over previous
//
#include <hip/hip_runtime.h>
#include <stdint.h>

// Problem: x[B=32][N=8192][D=64] fp32 -> out[B][D][D][D] fp32 (centered 3rd moment)
#define B_SZ 32
#define N_SZ 8192
#define D_SZ 64

typedef _Float16 half8 __attribute__((ext_vector_type(8)));
typedef float f32x4 __attribute__((ext_vector_type(4)));

#define AS1 __attribute__((address_space(1)))
#define AS3 __attribute__((address_space(3)))

#define MFMA16(Aop, Bop, Cop) __builtin_amdgcn_mfma_f32_16x16x32_f16(Aop, Bop, Cop, 0, 0, 0)

// Granule layout v1 (proven 0-conflict): per 64-n granule, chunk (d, cc)
// [8 halves, n = cc*8..+8] stored at d*64 + (cc ^ (d&7))*8 halves.
//
// v3 (R4): ej=2 (acc=80 -> AGPRs, R0-proven), single-reader granules, and
//   barrier-free main loop (wave-private dbuf, lgkmcnt(0) before overwrite,
//   vmcnt(8) pipeline). R4 counters validated the main loop: MfmaUtil-busy
//   time ~38us ~= the 41us matrix floor.
// v3.1 (this round): fix the epilogue scratch blowup. R4's store used
//   acc[h][idx] with RUNTIME h -> compiler materialized both acc arrays to
//   scratch (rule #20): WRITE_SIZE 33->245MB, +60us. Fix: statically bind
//   the accumulator via storeE(acc[0],...) / storeE(acc[1],...) under
//   wave-uniform branches; every index is compile-time again.

// ---------------------------------------------------------------------------
// Kernel 1: per-batch column sums. grid = 32 b * 32 slabs (256 n-rows each).
// ---------------------------------------------------------------------------
__global__ __launch_bounds__(256) void tp_mean_kernel(const float* __restrict__ x,
                                                      float* __restrict__ sums) {
    const int b    = blockIdx.x >> 5;
    const int slab = blockIdx.x & 31;
    const int d4   = threadIdx.x & 15;
    const int nr   = threadIdx.x >> 4;
    const float* base = x + (size_t)b * (N_SZ * D_SZ) + (size_t)(slab * 256 + nr) * D_SZ + d4 * 4;
    f32x4 s = {0.f, 0.f, 0.f, 0.f};
#pragma unroll
    for (int i = 0; i < 16; i++)
        s += *(const f32x4*)(base + i * 16 * D_SZ);
    __shared__ f32x4 red[16][16];
    red[nr][d4] = s;
    __syncthreads();
    if (threadIdx.x < 16) {
        f32x4 tot = red[0][threadIdx.x];
#pragma unroll
        for (int j = 1; j < 16; j++) tot += red[j][threadIdx.x];
        atomicAdd(&sums[b * 64 + threadIdx.x * 4 + 0], tot[0]);
        atomicAdd(&sums[b * 64 + threadIdx.x * 4 + 1], tot[1]);
        atomicAdd(&sums[b * 64 + threadIdx.x * 4 + 2], tot[2]);
        atomicAdd(&sums[b * 64 + threadIdx.x * 4 + 3], tot[3]);
    }
}

// ---------------------------------------------------------------------------
// Kernel 2: center, cast fp16, register transpose into layout v1 (verbatim).
// ---------------------------------------------------------------------------
__global__ __launch_bounds__(256) void tp_transpose_kernel(const float* __restrict__ x,
                                                           const float* __restrict__ sums,
                                                           _Float16* __restrict__ xcS) {
    const int b    = blockIdx.x >> 6;
    const int tp   = blockIdx.x & 63;
    const int t    = threadIdx.x;
    const int tile = tp * 2 + (t >> 7);
    const int r8   = (t >> 4) & 7;
    const int dq   = t & 15;

    f32x4 mean4 = *(const f32x4*)(sums + b * 64 + dq * 4) * (1.0f / (float)N_SZ);
    const float* src = x + (size_t)b * (N_SZ * D_SZ) + (size_t)(tile * 64 + r8 * 8) * D_SZ + dq * 4;
    f32x4 v[8];
#pragma unroll
    for (int i = 0; i < 8; i++)
        v[i] = *(const f32x4*)(src + i * D_SZ);

    _Float16* dstb = xcS + (size_t)b * (N_SZ * D_SZ) + (size_t)tile * 4096;
#pragma unroll
    for (int c = 0; c < 4; c++) {
        const int d   = dq * 4 + c;
        const int ccp = r8 ^ (d & 7);
        half8 o;
#pragma unroll
        for (int i = 0; i < 8; i++)
            o[i] = (_Float16)(v[i][c] - mean4[c]);
        *(half8*)(dstb + d * 64 + ccp * 8) = o;
    }
}

// ---------------------------------------------------------------------------
// Kernel 3 v3.1: grid (32 b, 32 eg), block 256 = 4 waves = 4 N-quarters,
// each wave computes ej=2 e-values (e0 = eg*2). LDS = 2 bufs x 4 h x 8KB.
// Per wave per T (one 64-n granule): 12 ds_read_b128 -> 40 MFMA;
// acc[2][10] = 80 regs in AGPRs. Barrier-free main loop, vmcnt(8) pipeline.
// 4-way cross-h reduction in two rounds; wave h=0 stores e0, h=1 stores e0+1
// via statically-bound storeE (no runtime acc indexing).
// ---------------------------------------------------------------------------
__global__ __launch_bounds__(256, 2) void tp_gemm_kernel(const _Float16* __restrict__ xcS,
                                                         float* __restrict__ out) {
    const int b    = blockIdx.x;          // 0..31
    const int eg   = blockIdx.y;          // 0..31
    const int tid  = threadIdx.x;
    const int lane = tid & 63;
    const int h    = tid >> 6;            // 0..3 N-quarter
    const int q    = lane >> 4;           // 0..3
    const int m    = lane & 15;
    const int e0   = eg * 2;

    __shared__ __align__(16) char ldsraw[65536];   // 2 bufs x 4 h x 8KB
    float* redL = (float*)ldsraw;                  // aliased for reduction (30KB)

    // staging source: wave h owns quarter h, one full 8KB granule per T
    const _Float16* gbase = xcS + (size_t)b * (N_SZ * D_SZ)
                          + (size_t)h * (N_SZ / 4) * D_SZ
                          + (size_t)(lane * 8);

    // fragment byte offsets (layout v1) for ks=0; ks=1 is offset ^ 64
    // (c = ks*4+q = q^4 for ks=1, and (x^4)*16 = x*16 ^ 64).
    int aOff[4], sOff[2];
#pragma unroll
    for (int i = 0; i < 4; i++) {
        const int r = i * 16 + m;
        aOff[i] = r * 128 + ((q ^ (r & 7)) * 16);
    }
#pragma unroll
    for (int j = 0; j < 2; j++) {
        const int e = e0 + j;
        sOff[j] = e * 128 + ((q ^ (e & 7)) * 16);
    }

    f32x4 acc[2][10];
#pragma unroll
    for (int ej = 0; ej < 2; ej++)
#pragma unroll
        for (int k = 0; k < 10; k++)
            acc[ej][k] = (f32x4){0.f, 0.f, 0.f, 0.f};

    // stage granule T of my quarter into buffer bi (wave-private 8KB region)
    auto stage = [&](int T, int bi) {
        _Float16* lb = (_Float16*)(ldsraw + bi * 32768 + h * 8192);
        const _Float16* gb = gbase + (size_t)T * 4096;
#pragma unroll
        for (int k = 0; k < 8; k++)
            __builtin_amdgcn_global_load_lds(
                (const AS1 void*)(gb + k * 512),
                (AS3 void*)(lb + k * 512), 16, 0, 0);
    };

    stage(0, 0);

    for (int T = 0; T < 32; T++) {
        if (T < 31) {
            // all prior ds_reads must have pulled their data out of the
            // buffer stage(T+1) is about to overwrite
            asm volatile("s_waitcnt lgkmcnt(0)" ::: "memory");
            stage(T + 1, (T + 1) & 1);
            // oldest 8 loads (granule T) done; next 8 stay in flight
            asm volatile("s_waitcnt vmcnt(8)" ::: "memory");
        } else {
            asm volatile("s_waitcnt vmcnt(0)" ::: "memory");
        }
        const char* tb = ldsraw + (T & 1) * 32768 + h * 8192;
#pragma unroll
        for (int ks = 0; ks < 2; ks++) {
            const int kx = ks << 6;
            half8 A0 = *(const half8*)(tb + (aOff[0] ^ kx));
            half8 A1 = *(const half8*)(tb + (aOff[1] ^ kx));
            half8 A2 = *(const half8*)(tb + (aOff[2] ^ kx));
            half8 A3 = *(const half8*)(tb + (aOff[3] ^ kx));
#pragma unroll
            for (int ej = 0; ej < 2; ej++) {
                half8 S  = *(const half8*)(tb + (sOff[ej] ^ kx));
                half8 P0 = A0 * S;    // fold xc[n,e] into A (v_pk_mul_f16)
                half8 P1 = A1 * S;
                half8 P2 = A2 * S;
                half8 P3 = A3 * S;
                acc[ej][0] = MFMA16(P0, A0, acc[ej][0]);
                acc[ej][1] = MFMA16(P0, A1, acc[ej][1]);
                acc[ej][2] = MFMA16(P0, A2, acc[ej][2]);
                acc[ej][3] = MFMA16(P0, A3, acc[ej][3]);
                acc[ej][4] = MFMA16(P1, A1, acc[ej][4]);
                acc[ej][5] = MFMA16(P1, A2, acc[ej][5]);
                acc[ej][6] = MFMA16(P1, A3, acc[ej][6]);
                acc[ej][7] = MFMA16(P2, A2, acc[ej][7]);
                acc[ej][8] = MFMA16(P2, A3, acc[ej][8]);
                acc[ej][9] = MFMA16(P3, A3, acc[ej][9]);
            }
        }
    }

    // ---- 4-way cross-h reduction, two rounds (30KB dumps each) ----
    __syncthreads();                      // end of main loop, LDS alias reuse
    const int rb = lane * 4;
    // round 0: h=1,2,3 dump acc[0]; h=0 gathers (owns e0)
    if (h != 0) {
        float* dst = redL + (h - 1) * 2560 + rb;
#pragma unroll
        for (int k = 0; k < 10; k++)
            *(f32x4*)(dst + k * 256) = acc[0][k];
    }
    __syncthreads();
    if (h == 0) {
#pragma unroll
        for (int k = 0; k < 10; k++) {
            const float* s0 = redL + k * 256 + rb;
            acc[0][k] += *(const f32x4*)(s0);
            acc[0][k] += *(const f32x4*)(s0 + 2560);
            acc[0][k] += *(const f32x4*)(s0 + 5120);
        }
    }
    __syncthreads();
    // round 1: h=0,2,3 dump acc[1]; h=1 gathers (owns e0+1)
    if (h != 1) {
        const int region = (h == 0) ? 0 : (h - 1);
        float* dst = redL + region * 2560 + rb;
#pragma unroll
        for (int k = 0; k < 10; k++)
            *(f32x4*)(dst + k * 256) = acc[1][k];
    }
    __syncthreads();
    if (h == 1) {
#pragma unroll
        for (int k = 0; k < 10; k++) {
            const float* s0 = redL + k * 256 + rb;
            acc[1][k] += *(const f32x4*)(s0);
            acc[1][k] += *(const f32x4*)(s0 + 2560);
            acc[1][k] += *(const f32x4*)(s0 + 5120);
        }
    }

    // ---- stores: statically-bound accumulator (rule #20: no runtime h
    // index into acc — R4's acc[h][idx] scratch'd 250MB). Wave h=0 stores
    // e0 from acc[0]; wave h=1 stores e0+1 from acc[1].
    const float invn = 1.0f / (float)N_SZ;
    float* outb = out + (size_t)b * (D_SZ * D_SZ * D_SZ);
    auto storeE = [&](const f32x4 (&accr)[10], int e) {
        int idx = 0;
        // C/D layout (verified): col = lane&15 = f-within-block, row = q*4+reg
#pragma unroll
        for (int i = 0; i < 4; i++) {
#pragma unroll
            for (int j = i; j < 4; j++, idx++) {
                f32x4 vsc = accr[idx] * invn;
#pragma unroll
                for (int r = 0; r < 4; r++)
                    outb[(size_t)(16 * i + q * 4 + r) * 4096 + e * 64 + 16 * j + m] = vsc[r];
                if (i != j) {
                    *(f32x4*)&outb[(size_t)(16 * j + m) * 4096 + e * 64 + 16 * i + q * 4] = vsc;
                }
            }
        }
    };
    if (h == 0) {
        storeE(acc[0], e0);
    } else if (h == 1) {
        storeE(acc[1], e0 + 1);
    }
}

// ---------------------------------------------------------------------------
extern "C" void kernel_launch(void* const* d_in, const int* in_sizes, int n_in,
                              void* d_out, int out_size, void* d_ws, size_t ws_size,
                              hipStream_t stream) {
    const float* x = (const float*)d_in[0];
    float* out = (float*)d_out;

    float* sums = (float*)d_ws;                           // 8 KB
    _Float16* xcS = (_Float16*)((char*)d_ws + 8192);      // 33.5 MB fp16

    hipMemsetAsync(sums, 0, B_SZ * D_SZ * sizeof(float), stream);
    tp_mean_kernel<<<dim3(B_SZ * 32), 256, 0, stream>>>(x, sums);
    tp_transpose_kernel<<<dim3(B_SZ * 64), 256, 0, stream>>>(x, sums, xcS);
    tp_gemm_kernel<<<dim3(32, 32), 256, 0, stream>>>(xcS, out);
}